// Round 9
// baseline (331.511 us; speedup 1.0000x reference)
//
#include <hip/hip_runtime.h>
#include <stdint.h>

// T-structure as a signed permutation: for each (k,p) there is exactly one q
// with sign s such that T[k,p,q] = s. Transcribed from _TERMS.
__constant__ signed char QTAB[64] = {
    0,1,2,3,4,5,6,7,
    1,0,4,5,2,3,7,6,
    2,4,0,6,1,7,3,5,
    3,5,6,0,7,1,2,4,
    4,2,1,7,0,6,5,3,
    5,3,7,1,6,0,4,2,
    6,7,3,2,5,4,0,1,
    7,6,5,4,3,2,1,0};
__constant__ signed char SGN[64] = {
    1, 1, 1, 1,-1,-1,-1,-1,
    1, 1,-1, 1, 1,-1,-1,-1,
    1, 1, 1,-1,-1, 1, 1,-1,
    1,-1, 1, 1,-1,-1,-1, 1,
    1, 1,-1, 1, 1,-1, 1,-1,
    1,-1, 1, 1, 1, 1,-1,-1,
    1,-1,-1, 1,-1, 1, 1, 1,
    1, 1,-1, 1, 1,-1, 1, 1};

// W2[iq][m] such that out[b][m] = sum_iq x[b][iq] * W2[iq][m]  (m = o*8+k,
// iq = i*8+q). Each entry written exactly once (QTAB rows are permutations).
__global__ void clifford_prep(const float* __restrict__ weight,
                              float* __restrict__ W2) {
    int t = threadIdx.x;
    for (int e = t; e < 4096; e += 256) {
        int o = e >> 9, i = (e >> 6) & 7, k = (e >> 3) & 7, p = e & 7;
        int q = (int)QTAB[k * 8 + p];
        float s = (float)SGN[k * 8 + p];
        W2[((i * 8 + q) * 64) + (o * 8 + k)] = s * weight[(o * 8 + i) * 8 + p];
    }
}

typedef __attribute__((address_space(1))) const float gfloat;
typedef __attribute__((address_space(3))) float sfloat;

#define SBAR __builtin_amdgcn_sched_barrier(0)
#define WAITVM(N)                                        \
    asm volatile("s_waitcnt vmcnt(" #N ")" ::: "memory"); \
    SBAR
#define WLGKM                                            \
    asm volatile("s_waitcnt lgkmcnt(0)" ::: "memory");   \
    SBAR

// Stage one 8-row chunk (8 x 64 f32 = 2 KB) linearly into LDS buffer BUF.
// Two 1-KB global_load_lds instrs; global src per-lane, LDS dest uniform
// (HW scatters lane*16). Perfectly coalesced; no swizzle needed since all
// LDS reads of this data are wave-uniform broadcasts (conflict-free).
#define ISSUE_CHUNK(CI, BUF)                                                 \
    {                                                                        \
        const float* src_ = x + (size_t)(CI) * 512 + (l << 2);               \
        __builtin_amdgcn_global_load_lds((gfloat*)(src_),                    \
                                         (sfloat*)(smw + (BUF) * 512), 16,   \
                                         0, 0);                              \
        __builtin_amdgcn_global_load_lds(                                    \
            (gfloat*)(src_ + 256), (sfloat*)(smw + (BUF) * 512 + 256), 16,   \
            0, 0);                                                           \
    }

// Compute + store one chunk: lane l owns output column m=l. Two groups of
// 4 rows; per group 4 independent FMA chains, x values come in as broadcast
// float4 LDS reads, W from per-lane registers. Stores: lane l writes
// out[row][l] -> 256 B contiguous per instruction.
#define DO_CHUNK(CI, BUF)                                                    \
    {                                                                        \
        float* ot_ = out + (size_t)(CI) * 512 + l;                           \
        _Pragma("unroll") for (int g_ = 0; g_ < 2; ++g_) {                   \
            float a0 = bv, a1 = bv, a2 = bv, a3 = bv;                        \
            const float* bp_ = smw + (BUF) * 512 + g_ * 256;                 \
            _Pragma("unroll") for (int j_ = 0; j_ < 16; ++j_) {              \
                float4 x0 = *(const float4*)(bp_ + 4 * j_);                  \
                float4 x1 = *(const float4*)(bp_ + 64 + 4 * j_);             \
                float4 x2 = *(const float4*)(bp_ + 128 + 4 * j_);            \
                float4 x3 = *(const float4*)(bp_ + 192 + 4 * j_);            \
                a0 = fmaf(x0.x, Wv[4 * j_ + 0], a0);                         \
                a1 = fmaf(x1.x, Wv[4 * j_ + 0], a1);                         \
                a2 = fmaf(x2.x, Wv[4 * j_ + 0], a2);                         \
                a3 = fmaf(x3.x, Wv[4 * j_ + 0], a3);                         \
                a0 = fmaf(x0.y, Wv[4 * j_ + 1], a0);                         \
                a1 = fmaf(x1.y, Wv[4 * j_ + 1], a1);                         \
                a2 = fmaf(x2.y, Wv[4 * j_ + 1], a2);                         \
                a3 = fmaf(x3.y, Wv[4 * j_ + 1], a3);                         \
                a0 = fmaf(x0.z, Wv[4 * j_ + 2], a0);                         \
                a1 = fmaf(x1.z, Wv[4 * j_ + 2], a1);                         \
                a2 = fmaf(x2.z, Wv[4 * j_ + 2], a2);                         \
                a3 = fmaf(x3.z, Wv[4 * j_ + 2], a3);                         \
                a0 = fmaf(x0.w, Wv[4 * j_ + 3], a0);                         \
                a1 = fmaf(x1.w, Wv[4 * j_ + 3], a1);                         \
                a2 = fmaf(x2.w, Wv[4 * j_ + 3], a2);                         \
                a3 = fmaf(x3.w, Wv[4 * j_ + 3], a3);                         \
            }                                                                \
            ot_[(g_ * 4 + 0) * 64] = a0;                                     \
            ot_[(g_ * 4 + 1) * 64] = a1;                                     \
            ot_[(g_ * 4 + 2) * 64] = a2;                                     \
            ot_[(g_ * 4 + 3) * 64] = a3;                                     \
        }                                                                    \
    }

// lane = output index m: W column in 64 VGPRs (loaded once), x broadcast
// from LDS, coalesced stores, no transposes. __launch_bounds__(256,4) is
// the R5 fix: 128-VGPR budget so Wv[64] STAYS IN REGISTERS (R5's implicit
// 64-VGPR target spilled it -> VGPR_Count=56, VALUBusy 80%, 331 us).
__global__ __launch_bounds__(256, 4) void clifford_main(
    const float* __restrict__ x, const float* __restrict__ W,
    const float* __restrict__ bias, float* __restrict__ out, int nB) {
    __shared__ __align__(16) float smem[4][1024];  // 2 buffers x 512 f32/wave
    const int l = threadIdx.x & 63;
    const int wv = threadIdx.x >> 6;
    float* smw = smem[wv];
    const int nC = nB >> 3;  // 8-row chunks
    const long long nW = (long long)gridDim.x * 4;
    const long long w = (long long)blockIdx.x * 4 + wv;
    const int cpw = (int)(nC / nW);
    const long long rem = nC - (long long)cpw * nW;

    float Wv[64];
#pragma unroll
    for (int iq = 0; iq < 64; ++iq) Wv[iq] = W[iq * 64 + l];
    const float bv = bias[l];

    const long long c0 = w * cpw;
    if (cpw >= 3) {
        ISSUE_CHUNK(c0, 0);
        ISSUE_CHUNK(c0 + 1, 1);
        WAITVM(2);  // chunk c0 staged (also drains Wv/bias loads)
        for (int i = 0; i < cpw - 2; ++i) {
            const long long c = c0 + i;
            if ((i & 1) == 0) {
                DO_CHUNK(c, 0);
                WLGKM;  // chunk's ds_reads consumed -> safe to overwrite
                ISSUE_CHUNK(c + 2, 0);
            } else {
                DO_CHUNK(c, 1);
                WLGKM;
                ISSUE_CHUNK(c + 2, 1);
            }
            // queue: [L(c+1):2, S(c):8, L(c+2):2] -> retire exactly L(c+1)
            WAITVM(10);
        }
        if (((cpw - 2) & 1) == 0) {
            DO_CHUNK(c0 + cpw - 2, 0);
        } else {
            DO_CHUNK(c0 + cpw - 2, 1);
        }
        // queue <= [S(prev):8, L(last):2, S(this):8] -> vmcnt(8) retires
        // everything through L(last)
        WAITVM(8);
        if (((cpw - 1) & 1) == 0) {
            DO_CHUNK(c0 + cpw - 1, 0);
        } else {
            DO_CHUNK(c0 + cpw - 1, 1);
        }
    } else {
        for (int i = 0; i < cpw; ++i) {
            ISSUE_CHUNK(c0 + i, 0);
            WAITVM(0);
            DO_CHUNK(c0 + i, 0);
            WLGKM;
        }
    }
    if (w < rem) {  // leftover chunks (0 for the bench shape)
        const long long c = nW * cpw + w;
        WAITVM(0);
        ISSUE_CHUNK(c, 0);
        WAITVM(0);
        DO_CHUNK(c, 0);
    }
}

extern "C" void kernel_launch(void* const* d_in, const int* in_sizes, int n_in,
                              void* d_out, int out_size, void* d_ws,
                              size_t ws_size, hipStream_t stream) {
    const float* x = (const float*)d_in[0];
    const float* weight = (const float*)d_in[1];
    const float* bias = (const float*)d_in[2];
    float* out = (float*)d_out;
    float* W2 = (float*)d_ws;  // 4096 floats = 16 KB scratch

    int nB = in_sizes[0] / 64;  // 4096*512 batch elements

    hipLaunchKernelGGL(clifford_prep, dim3(1), dim3(256), 0, stream, weight,
                       W2);
    int nC = nB >> 3;
    int blocks = 2048;  // 8192 waves -> exactly 32 chunks/wave at nB=2^21
    if (blocks * 4 > nC) blocks = (nC + 3) / 4;
    if (blocks < 1) blocks = 1;
    hipLaunchKernelGGL(clifford_main, dim3(blocks), dim3(256), 0, stream, x,
                       W2, bias, out, nB);
}

// Round 13
// 329.887 us; speedup vs baseline: 1.0049x; 1.0049x over previous
//
#include <hip/hip_runtime.h>
#include <stdint.h>

// T-structure as a signed permutation: for each (k,p) there is exactly one q
// with sign s such that T[k,p,q] = s. Transcribed from _TERMS.
__constant__ signed char QTAB[64] = {
    0,1,2,3,4,5,6,7,
    1,0,4,5,2,3,7,6,
    2,4,0,6,1,7,3,5,
    3,5,6,0,7,1,2,4,
    4,2,1,7,0,6,5,3,
    5,3,7,1,6,0,4,2,
    6,7,3,2,5,4,0,1,
    7,6,5,4,3,2,1,0};
__constant__ signed char SGN[64] = {
    1, 1, 1, 1,-1,-1,-1,-1,
    1, 1,-1, 1, 1,-1,-1,-1,
    1, 1, 1,-1,-1, 1, 1,-1,
    1,-1, 1, 1,-1,-1,-1, 1,
    1, 1,-1, 1, 1,-1, 1,-1,
    1,-1, 1, 1, 1, 1,-1,-1,
    1,-1,-1, 1,-1, 1, 1, 1,
    1, 1,-1, 1, 1,-1, 1, 1};

// W2[iq][m] such that out[b][m] = sum_iq x[b][iq] * W2[iq][m]  (m = o*8+k,
// iq = i*8+q). Each entry written exactly once (QTAB rows are permutations).
__global__ void clifford_prep(const float* __restrict__ weight,
                              float* __restrict__ W2) {
    int t = threadIdx.x;
    for (int e = t; e < 4096; e += 256) {
        int o = e >> 9, i = (e >> 6) & 7, k = (e >> 3) & 7, p = e & 7;
        int q = (int)QTAB[k * 8 + p];
        float s = (float)SGN[k * 8 + p];
        W2[((i * 8 + q) * 64) + (o * 8 + k)] = s * weight[(o * 8 + i) * 8 + p];
    }
}

typedef __attribute__((address_space(1))) const float gfloat;
typedef __attribute__((address_space(3))) float sfloat;

#define SBAR __builtin_amdgcn_sched_barrier(0)
#define WAITVM(N)                                        \
    asm volatile("s_waitcnt vmcnt(" #N ")" ::: "memory"); \
    SBAR
#define WLGKM                                            \
    asm volatile("s_waitcnt lgkmcnt(0)" ::: "memory");   \
    SBAR

// Stage one 8-row chunk (8 x 64 f32 = 2 KB) linearly into LDS buffer BUF.
// Two 1-KB global_load_lds instrs; global src per-lane, LDS dest uniform
// (HW scatters lane*16). Perfectly coalesced; no swizzle needed since all
// LDS reads of this data are wave-uniform broadcasts (conflict-free).
#define ISSUE_CHUNK(CI, BUF)                                                 \
    {                                                                        \
        const float* src_ = x + (size_t)(CI) * 512 + (l << 2);               \
        __builtin_amdgcn_global_load_lds((gfloat*)(src_),                    \
                                         (sfloat*)(smw + (BUF) * 512), 16,   \
                                         0, 0);                              \
        __builtin_amdgcn_global_load_lds(                                    \
            (gfloat*)(src_ + 256), (sfloat*)(smw + (BUF) * 512 + 256), 16,   \
            0, 0);                                                           \
    }

// Compute + store one chunk: lane l owns output column m=l. Two groups of
// 4 rows; per group 4 independent FMA chains, x values come in as broadcast
// float4 LDS reads, W from per-lane registers. Stores: lane l writes
// out[row][l] -> 256 B contiguous per instruction.
#define DO_CHUNK(CI, BUF)                                                    \
    {                                                                        \
        float* ot_ = out + (size_t)(CI) * 512 + l;                           \
        _Pragma("unroll") for (int g_ = 0; g_ < 2; ++g_) {                   \
            float a0 = bv, a1 = bv, a2 = bv, a3 = bv;                        \
            const float* bp_ = smw + (BUF) * 512 + g_ * 256;                 \
            _Pragma("unroll") for (int j_ = 0; j_ < 16; ++j_) {              \
                float4 x0 = *(const float4*)(bp_ + 4 * j_);                  \
                float4 x1 = *(const float4*)(bp_ + 64 + 4 * j_);             \
                float4 x2 = *(const float4*)(bp_ + 128 + 4 * j_);            \
                float4 x3 = *(const float4*)(bp_ + 192 + 4 * j_);            \
                a0 = fmaf(x0.x, Wv[4 * j_ + 0], a0);                         \
                a1 = fmaf(x1.x, Wv[4 * j_ + 0], a1);                         \
                a2 = fmaf(x2.x, Wv[4 * j_ + 0], a2);                         \
                a3 = fmaf(x3.x, Wv[4 * j_ + 0], a3);                         \
                a0 = fmaf(x0.y, Wv[4 * j_ + 1], a0);                         \
                a1 = fmaf(x1.y, Wv[4 * j_ + 1], a1);                         \
                a2 = fmaf(x2.y, Wv[4 * j_ + 1], a2);                         \
                a3 = fmaf(x3.y, Wv[4 * j_ + 1], a3);                         \
                a0 = fmaf(x0.z, Wv[4 * j_ + 2], a0);                         \
                a1 = fmaf(x1.z, Wv[4 * j_ + 2], a1);                         \
                a2 = fmaf(x2.z, Wv[4 * j_ + 2], a2);                         \
                a3 = fmaf(x3.z, Wv[4 * j_ + 2], a3);                         \
                a0 = fmaf(x0.w, Wv[4 * j_ + 3], a0);                         \
                a1 = fmaf(x1.w, Wv[4 * j_ + 3], a1);                         \
                a2 = fmaf(x2.w, Wv[4 * j_ + 3], a2);                         \
                a3 = fmaf(x3.w, Wv[4 * j_ + 3], a3);                         \
            }                                                                \
            ot_[(g_ * 4 + 0) * 64] = a0;                                     \
            ot_[(g_ * 4 + 1) * 64] = a1;                                     \
            ot_[(g_ * 4 + 2) * 64] = a2;                                     \
            ot_[(g_ * 4 + 3) * 64] = a3;                                     \
        }                                                                    \
    }

// lane = output index m: W column in 64 VGPRs, x broadcast from LDS,
// coalesced stores, no transposes.
// R8 lesson: launch_bounds(256,4) only CAPS VGPRs; the allocator still
// targeted 8 waves/EU (VGPR=64) by REMATERIALIZING the Wv loads each use
// (VALUBusy 81%). Fix: (a) amdgpu_waves_per_eu(4,4) hard range -> no
// incentive to shrink below 128; (b) empty-asm pins make the asm the
// definer of each Wv value -> remat from the original load is illegal.
__global__ __attribute__((amdgpu_waves_per_eu(4, 4)))
__launch_bounds__(256) void clifford_main(
    const float* __restrict__ x, const float* __restrict__ W,
    const float* __restrict__ bias, float* __restrict__ out, int nB) {
    __shared__ __align__(16) float smem[4][1024];  // 2 buffers x 512 f32/wave
    const int l = threadIdx.x & 63;
    const int wv = threadIdx.x >> 6;
    float* smw = smem[wv];
    const int nC = nB >> 3;  // 8-row chunks
    const long long nW = (long long)gridDim.x * 4;
    const long long w = (long long)blockIdx.x * 4 + wv;
    const int cpw = (int)(nC / nW);
    const long long rem = nC - (long long)cpw * nW;

    float Wv[64];
#pragma unroll
    for (int iq = 0; iq < 64; ++iq) Wv[iq] = W[iq * 64 + l];
    float bv = bias[l];
    // Anti-remat pins: force each value to be defined by an opaque asm so
    // the allocator must keep it in a VGPR (or true-spill, which it won't
    // at a 128-VGPR budget) instead of re-loading from W on every use.
#pragma unroll
    for (int iq = 0; iq < 64; ++iq) asm volatile("" : "+v"(Wv[iq]));
    asm volatile("" : "+v"(bv));

    const long long c0 = w * cpw;
    if (cpw >= 3) {
        ISSUE_CHUNK(c0, 0);
        ISSUE_CHUNK(c0 + 1, 1);
        WAITVM(2);  // chunk c0 staged (Wv loads already drained by pins)
        for (int i = 0; i < cpw - 2; ++i) {
            const long long c = c0 + i;
            if ((i & 1) == 0) {
                DO_CHUNK(c, 0);
                WLGKM;  // chunk's ds_reads consumed -> safe to overwrite
                ISSUE_CHUNK(c + 2, 0);
            } else {
                DO_CHUNK(c, 1);
                WLGKM;
                ISSUE_CHUNK(c + 2, 1);
            }
            // queue: [L(c+1):2, S(c):8, L(c+2):2] -> retire exactly L(c+1)
            WAITVM(10);
        }
        if (((cpw - 2) & 1) == 0) {
            DO_CHUNK(c0 + cpw - 2, 0);
        } else {
            DO_CHUNK(c0 + cpw - 2, 1);
        }
        // queue <= [S(prev):8, L(last):2, S(this):8] -> vmcnt(8) retires
        // everything through L(last)
        WAITVM(8);
        if (((cpw - 1) & 1) == 0) {
            DO_CHUNK(c0 + cpw - 1, 0);
        } else {
            DO_CHUNK(c0 + cpw - 1, 1);
        }
    } else {
        for (int i = 0; i < cpw; ++i) {
            ISSUE_CHUNK(c0 + i, 0);
            WAITVM(0);
            DO_CHUNK(c0 + i, 0);
            WLGKM;
        }
    }
    if (w < rem) {  // leftover chunks (0 for the bench shape)
        const long long c = nW * cpw + w;
        WAITVM(0);
        ISSUE_CHUNK(c, 0);
        WAITVM(0);
        DO_CHUNK(c, 0);
    }
}

extern "C" void kernel_launch(void* const* d_in, const int* in_sizes, int n_in,
                              void* d_out, int out_size, void* d_ws,
                              size_t ws_size, hipStream_t stream) {
    const float* x = (const float*)d_in[0];
    const float* weight = (const float*)d_in[1];
    const float* bias = (const float*)d_in[2];
    float* out = (float*)d_out;
    float* W2 = (float*)d_ws;  // 4096 floats = 16 KB scratch

    int nB = in_sizes[0] / 64;  // 4096*512 batch elements

    hipLaunchKernelGGL(clifford_prep, dim3(1), dim3(256), 0, stream, weight,
                       W2);
    int nC = nB >> 3;
    int blocks = 2048;  // 8192 waves -> exactly 32 chunks/wave at nB=2^21
    if (blocks * 4 > nC) blocks = (nC + 3) / 4;
    if (blocks < 1) blocks = 1;
    hipLaunchKernelGGL(clifford_main, dim3(blocks), dim3(256), 0, stream, x,
                       W2, bias, out, nB);
}

// Round 14
// 221.491 us; speedup vs baseline: 1.4967x; 1.4894x over previous
//
#include <hip/hip_runtime.h>
#include <hip/hip_bf16.h>
#include <stdint.h>

// T-structure as a signed permutation: for each (k,p) exactly one q with
// sign s such that T[k,p,q] = s. Transcribed from _TERMS.
__constant__ signed char QTAB[64] = {
    0,1,2,3,4,5,6,7,
    1,0,4,5,2,3,7,6,
    2,4,0,6,1,7,3,5,
    3,5,6,0,7,1,2,4,
    4,2,1,7,0,6,5,3,
    5,3,7,1,6,0,4,2,
    6,7,3,2,5,4,0,1,
    7,6,5,4,3,2,1,0};
__constant__ signed char SGN[64] = {
    1, 1, 1, 1,-1,-1,-1,-1,
    1, 1,-1, 1, 1,-1,-1,-1,
    1, 1, 1,-1,-1, 1, 1,-1,
    1,-1, 1, 1,-1,-1,-1, 1,
    1, 1,-1, 1, 1,-1, 1,-1,
    1,-1, 1, 1, 1, 1,-1,-1,
    1,-1,-1, 1,-1, 1, 1, 1,
    1, 1,-1, 1, 1,-1, 1, 1};

typedef __attribute__((ext_vector_type(8))) short bf16x8;
typedef __attribute__((ext_vector_type(4))) float f32x4;
typedef __attribute__((ext_vector_type(4))) unsigned int u32x4;
typedef __attribute__((address_space(1))) const float gfloat;
typedef __attribute__((address_space(3))) float sfloat;

#define SBAR __builtin_amdgcn_sched_barrier(0)
#define WAITVM(N)                                         \
    asm volatile("s_waitcnt vmcnt(" #N ")" ::: "memory"); \
    SBAR

// prep: phase 1 builds W2[iq][m] fp32 (4096 f); phase 2 builds W2T bf16
// [m][iq] (4096 ushort) for MFMA B-fragments (k-contiguous per output col).
__global__ void clifford_prep(const float* __restrict__ weight,
                              float* __restrict__ W2,
                              unsigned short* __restrict__ W2T) {
    int t = threadIdx.x;
    for (int e = t; e < 4096; e += 256) {
        int o = e >> 9, i = (e >> 6) & 7, k = (e >> 3) & 7, p = e & 7;
        int q = (int)QTAB[k * 8 + p];
        float s = (float)SGN[k * 8 + p];
        W2[((i * 8 + q) * 64) + (o * 8 + k)] = s * weight[(o * 8 + i) * 8 + p];
    }
    __syncthreads();
    for (int e = t; e < 4096; e += 256) {
        int n = e >> 6, k = e & 63;
        __hip_bfloat16 h = __float2bfloat16(W2[k * 64 + n]);
        W2T[n * 64 + k] = *reinterpret_cast<unsigned short*>(&h);
    }
}

static __device__ __forceinline__ short f2bf(float f) {
    __hip_bfloat16 h = __float2bfloat16(f);
    return *reinterpret_cast<short*>(&h);
}

// Stage one 32-row chunk (32 x 64 fp32 = 8 KB) into LDS via global_load_lds.
// LDS dest is linear; the A-fragment bank swizzle is applied on the per-lane
// GLOBAL source: quad q of row r holds global quad (q ^ (r&15)).
// (Both-sides rule; this exact pattern passed absmax 0.0 in R4.)
#define ISSUE_CHUNK(CI, BP)                                                  \
    {                                                                        \
        const float* base_ = x + (size_t)(CI) * 2048;                        \
        _Pragma("unroll") for (int i_ = 0; i_ < 8; ++i_) {                   \
            int r_ = i_ * 4 + (l >> 4);                                      \
            const float* src_ =                                              \
                base_ + r_ * 64 + (((l & 15) ^ (r_ & 15)) << 2);             \
            __builtin_amdgcn_global_load_lds(                                \
                (gfloat*)src_, (sfloat*)((BP) + i_ * 256 + (l << 2)), 16, 0, \
                0);                                                          \
        }                                                                    \
    }

// MFMA compute of one staged chunk: acc[mt][nt] (2x4 tiles of 16x16).
// A: lane holds row mt*16+(l&15), k = kh*32 + 8*(l>>4) + e (fp32 -> bf16).
// B: from block-shared swizzled W2T LDS; lane holds col nt*16+(l&15),
//    same k-run. D: col = l&15, row = 4*(l>>4)+reg  [m89-verified].
#define COMPUTE(BP)                                                          \
    {                                                                        \
        _Pragma("unroll") for (int kh = 0; kh < 2; ++kh) {                   \
            bf16x8 afr[2];                                                   \
            _Pragma("unroll") for (int mt = 0; mt < 2; ++mt) {               \
                int r_ = mt * 16 + (l & 15);                                 \
                int qa = kh * 8 + 2 * (l >> 4);                              \
                float4 lo = *(const float4*)((BP) + r_ * 64 +                \
                                             ((qa ^ (r_ & 15)) << 2));       \
                float4 hi = *(const float4*)((BP) + r_ * 64 +                \
                                             (((qa + 1) ^ (r_ & 15)) << 2)); \
                bf16x8 a_;                                                   \
                a_[0] = f2bf(lo.x); a_[1] = f2bf(lo.y);                      \
                a_[2] = f2bf(lo.z); a_[3] = f2bf(lo.w);                      \
                a_[4] = f2bf(hi.x); a_[5] = f2bf(hi.y);                      \
                a_[6] = f2bf(hi.z); a_[7] = f2bf(hi.w);                      \
                afr[mt] = a_;                                                \
            }                                                                \
            _Pragma("unroll") for (int nt = 0; nt < 4; ++nt) {               \
                int n_ = nt * 16 + (l & 15);                                 \
                int qb = kh * 4 + (l >> 4);                                  \
                bf16x8 bfr = *(const bf16x8*)((const char*)w2t + n_ * 128 +  \
                                              (((qb ^ (n_ & 7))) << 4));     \
                acc[0][nt] = __builtin_amdgcn_mfma_f32_16x16x32_bf16(        \
                    afr[0], bfr, acc[0][nt], 0, 0, 0);                       \
                acc[1][nt] = __builtin_amdgcn_mfma_f32_16x16x32_bf16(        \
                    afr[1], bfr, acc[1][nt], 0, 0, 0);                       \
            }                                                                \
        }                                                                    \
    }

// Transpose acc through the (now dead) X buffer, then 1-KB coalesced stores.
#define STORE_CHUNK(CI, BP)                                                  \
    {                                                                        \
        _Pragma("unroll") for (int mt = 0; mt < 2; ++mt)                     \
        _Pragma("unroll") for (int nt = 0; nt < 4; ++nt)                     \
        _Pragma("unroll") for (int rg = 0; rg < 4; ++rg) {                   \
            int row_ = mt * 16 + 4 * (l >> 4) + rg;                          \
            (BP)[row_ * 64 + nt * 16 + (l & 15)] = acc[mt][nt][rg];          \
        }                                                                    \
        float* ob_ = out + (size_t)(CI) * 2048;                              \
        _Pragma("unroll") for (int j_ = 0; j_ < 8; ++j_) {                   \
            float4 v_ = *(const float4*)((BP) + j_ * 256 + (l << 2));        \
            *(float4*)(ob_ + j_ * 256 + (l << 2)) = v_;                      \
        }                                                                    \
    }

#define ACC_INIT                                                 \
    f32x4 acc[2][4];                                             \
    _Pragma("unroll") for (int mt = 0; mt < 2; ++mt)             \
    _Pragma("unroll") for (int nt = 0; nt < 4; ++nt) {           \
        acc[mt][nt][0] = bvv[nt]; acc[mt][nt][1] = bvv[nt];      \
        acc[mt][nt][2] = bvv[nt]; acc[mt][nt][3] = bvv[nt];      \
    }

__global__ __launch_bounds__(256) void clifford_main(
    const float* __restrict__ x, const unsigned short* __restrict__ W2T,
    const float* __restrict__ bias, float* __restrict__ out, int nB) {
    __shared__ __align__(16) float xbuf[4][2][2048];      // 64 KB
    __shared__ __align__(16) unsigned short w2t[4096];    // 8 KB, swizzled

    const int tid = threadIdx.x;
    const int l = tid & 63;
    const int wv = tid >> 6;

    // ---- block-shared W2T init (swizzled quads), one barrier only ----
#pragma unroll
    for (int gg = 0; gg < 2; ++gg) {
        int g = tid * 2 + gg;          // 512 quads of 16 B
        int n = g >> 3, q = g & 7;
        u32x4 v = *(const u32x4*)(W2T + n * 64 + q * 8);
        *(u32x4*)((char*)w2t + n * 128 + ((q ^ (n & 7)) << 4)) = v;
    }
    __syncthreads();

    float* xb0 = xbuf[wv][0];
    float* xb1 = xbuf[wv][1];
    const int nC = nB >> 5;  // 32-row chunks
    const long long nW = (long long)gridDim.x * 4;
    const long long w = (long long)blockIdx.x * 4 + wv;
    const int cpw = (int)(nC / nW);
    const long long rem = nC - (long long)cpw * nW;

    float bvv[4];
#pragma unroll
    for (int nt = 0; nt < 4; ++nt) bvv[nt] = bias[nt * 16 + (l & 15)];
#pragma unroll
    for (int nt = 0; nt < 4; ++nt) asm volatile("" : "+v"(bvv[nt]));
    // pins drain the bias loads now -> vm queue below holds ONLY our ops

    const long long c0 = w * cpw;
    if (cpw >= 3) {
        ISSUE_CHUNK(c0, xb0);
        ISSUE_CHUNK(c0 + 1, xb1);
        WAITVM(8);  // chunk c0 staged; L(c0+1):8 in flight
        for (int i = 0; i < cpw - 2; ++i) {
            float* bp = (i & 1) ? xb1 : xb0;
            const long long c = c0 + i;
            ACC_INIT;
            COMPUTE(bp);
            STORE_CHUNK(c, bp);   // +8 stores
            SBAR;                 // keep DMA issue after the LDS readback
            ISSUE_CHUNK(c + 2, bp);  // +8 loads
            // queue: S(c-1):8, L(c+1):8, S(c):8, L(c+2):8 -> retire L(c+1)
            WAITVM(16);
        }
        {   // chunk c0+cpw-2 (loads already retired by last WAITVM(16))
            float* bp = ((cpw - 2) & 1) ? xb1 : xb0;
            ACC_INIT;
            COMPUTE(bp);
            STORE_CHUNK(c0 + cpw - 2, bp);
            SBAR;
            // queue: S(old):8, L(last):8, S(this):8 -> retire L(last)
            WAITVM(8);
        }
        {   // final chunk
            float* bp = ((cpw - 1) & 1) ? xb1 : xb0;
            ACC_INIT;
            COMPUTE(bp);
            STORE_CHUNK(c0 + cpw - 1, bp);
        }
    } else {
        for (int i = 0; i < cpw; ++i) {
            ISSUE_CHUNK(c0 + i, xb0);
            WAITVM(0);
            ACC_INIT;
            COMPUTE(xb0);
            STORE_CHUNK(c0 + i, xb0);
            WAITVM(0);
        }
    }
    if (w < rem) {  // leftover chunks (0 at the bench shape)
        const long long c = nW * cpw + w;
        WAITVM(0);
        ISSUE_CHUNK(c, xb0);
        WAITVM(0);
        ACC_INIT;
        COMPUTE(xb0);
        STORE_CHUNK(c, xb0);
    }
}

extern "C" void kernel_launch(void* const* d_in, const int* in_sizes, int n_in,
                              void* d_out, int out_size, void* d_ws,
                              size_t ws_size, hipStream_t stream) {
    const float* x = (const float*)d_in[0];
    const float* weight = (const float*)d_in[1];
    const float* bias = (const float*)d_in[2];
    float* out = (float*)d_out;
    float* W2 = (float*)d_ws;                              // 16 KB
    unsigned short* W2T = (unsigned short*)(W2 + 4096);    // +8 KB

    int nB = in_sizes[0] / 64;  // 4096*512 batch elements

    hipLaunchKernelGGL(clifford_prep, dim3(1), dim3(256), 0, stream, weight,
                       W2, W2T);
    int nC = nB >> 5;
    int blocks = 2048;  // 8192 waves -> 8 chunks/wave at nB=2^21
    if (blocks * 4 > nC) blocks = (nC + 3) / 4;
    if (blocks < 1) blocks = 1;
    hipLaunchKernelGGL(clifford_main, dim3(blocks), dim3(256), 0, stream, x,
                       W2T, bias, out, nB);
}